// Round 16
// baseline (325.663 us; speedup 1.0000x reference)
//
#include <hip/hip_runtime.h>
#include <hip/hip_bf16.h>

typedef short short8 __attribute__((ext_vector_type(8)));
typedef float floatx4 __attribute__((ext_vector_type(4)));
typedef float floatx4v __attribute__((ext_vector_type(4)));

#define SCALE_F 0.10206207261596575f
#define TOKSTRIDE 401424   // 25089 * 16

static __device__ __forceinline__ float b2f(unsigned short u){
  unsigned int v = ((unsigned int)u) << 16; float f;
  __builtin_memcpy(&f, &v, 4); return f;
}
static __device__ __forceinline__ unsigned short f2b(float f){
  __hip_bfloat16 h = __float2bfloat16(f);
  unsigned short u; __builtin_memcpy(&u, &h, 2); return u;
}
static __device__ __forceinline__ int map20(int i){
  return (i < 2) ? i : 7 + ((i-2)/3)*8 + ((i-2)%3);
}

// uniform per-block dtype probe: all threads read the same 32 words of x -> same flag
static __device__ __forceinline__ int detect_f32(const void* x){
  const unsigned int* xw = (const unsigned int*)x;
  int c = 0;
  #pragma unroll
  for (int i = 0; i < 32; ++i){
    unsigned int w = xw[1024 + i];
    int e = (w >> 7) & 0xFF;
    c += (e >= 90 && e <= 140) ? 1 : 0;
  }
  return (c < 20) ? 1 : 0;     // fp32 mantissa bits rarely look like bf16 exponents
}

// flag-aware 8-element fragment load (fp32 -> bf16 cvt, or direct bf16)
static __device__ __forceinline__ short8 load_frag8(const void* p_, int flag, size_t off){
  if (flag){
    const float* p = (const float*)p_ + off;
    floatx4v f0 = *(const floatx4v*)(p);
    floatx4v f1 = *(const floatx4v*)(p + 4);
    short8 o;
    #pragma unroll
    for (int j = 0; j < 4; ++j){ o[j] = (short)f2b(f0[j]); o[j+4] = (short)f2b(f1[j]); }
    return o;
  } else {
    return *(const short8*)((const unsigned short*)p_ + off);
  }
}
static __device__ __forceinline__ float ldf(const void* p, int flag, int i){
  return flag ? ((const float*)p)[i] : b2f(((const unsigned short*)p)[i]);
}

// load one 16-row A-fragment triple from x (flag-dependent dtype)
static __device__ __forceinline__ void load_x_frag(
    const void* xr_, int flag, size_t elem_off, short8& a0, short8& a1, short8& a2)
{
  a0 = load_frag8(xr_, flag, elem_off);
  a1 = load_frag8(xr_, flag, elem_off + 32);
  a2 = load_frag8(xr_, flag, elem_off + 64);
}

// ---------------- K1: merged QKV GEMM (self-converting) ----------------
__global__ __launch_bounds__(256) void k_qkv(
    const void* __restrict__ x, const void* __restrict__ w,
    const void* __restrict__ bias, unsigned short* __restrict__ qr,
    unsigned short* __restrict__ kc, unsigned short* __restrict__ vc,
    unsigned short* __restrict__ kcls, unsigned short* __restrict__ vcls)
{
  const int flag = detect_f32(x);
  const int lane = threadIdx.x & 63;
  const int wv = threadIdx.x >> 6;
  const int kq = (lane >> 4) * 8;
  const int quad = lane >> 4;
  const int col_l = lane & 15;

  if (blockIdx.x < 1569){
    // ---- Q path ----
    const int m_base = blockIdx.x * 64 + wv * 16;
    int ma = m_base + col_l; if (ma > 100355) ma = 100355;
    short8 a0, a1, a2;
    load_x_frag(x, flag, (size_t)ma*96 + kq, a0, a1, a2);

    int bbase[4], ntok[4], mrow[4];
    #pragma unroll
    for (int r = 0; r < 4; ++r){
      int m = m_base + quad*4 + r;
      mrow[r] = m;
      int bb = m / 25089;
      ntok[r] = m - bb*25089;
      bbase[r] = bb*2;
    }

    #pragma unroll
    for (int ct = 0; ct < 12; ++ct){
      int col = ct*16 + col_l;
      short8 b0 = load_frag8(w, flag, (size_t)col*96 + kq);
      short8 b1 = load_frag8(w, flag, (size_t)col*96 + kq + 32);
      short8 b2 = load_frag8(w, flag, (size_t)col*96 + kq + 64);
      float bv = ldf(bias, flag, col);
      floatx4 acc = {0.f,0.f,0.f,0.f};
      acc = __builtin_amdgcn_mfma_f32_16x16x32_bf16(a0, b0, acc, 0,0,0);
      acc = __builtin_amdgcn_mfma_f32_16x16x32_bf16(a1, b1, acc, 0,0,0);
      acc = __builtin_amdgcn_mfma_f32_16x16x32_bf16(a2, b2, acc, 0,0,0);
      const int head = ct / 6;
      const int dt6  = ct % 6;
      #pragma unroll
      for (int r = 0; r < 4; ++r){
        if (mrow[r] < 100356)
          qr[(size_t)((bbase[r]+head)*6 + dt6)*TOKSTRIDE + (size_t)ntok[r]*16 + col_l]
            = f2b(acc[r] + bv);
      }
    }
  } else {
    // ---- KV path ----
    const int id = blockIdx.x - 1569;
    const int isv = id / 201;
    const int bx = id - isv*201;
    const int rbase = bx * 64 + wv * 16;

    int rhoA = rbase + col_l; if (rhoA > 12803) rhoA = 12803;
    int bA, nA;
    if (rhoA < 4){ bA = rhoA; nA = 0; }
    else {
      int rp = rhoA - 4;
      bA = rp / 3200; int rem = rp - bA*3200;
      int t = rem / 400; int s = rem - t*400;
      int ry = s / 20, rx = s - ry*20;
      nA = 1 + (t*56 + map20(ry))*56 + map20(rx);
    }
    short8 a0, a1, a2;
    load_x_frag(x, flag, ((size_t)bA*25089 + nA)*96 + kq, a0, a1, a2);

    int isCls[4], bI[4], baseI[4], valid[4];
    #pragma unroll
    for (int r = 0; r < 4; ++r){
      int rho = rbase + quad*4 + r;
      valid[r] = (rho < 12804);
      if (rho > 12803) rho = 12803;
      if (rho < 4){ isCls[r] = 1; bI[r] = rho; baseI[r] = 0; }
      else {
        int rp = rho - 4;
        int b = rp / 3200; int rem = rp - b*3200;
        int t = rem / 400; int s = rem - t*400;
        int ry = s / 20, rx = s - ry*20;
        isCls[r] = 0; bI[r] = b;
        baseI[r] = (((b*8 + t)*20 + ry)*20 + rx)*192;
      }
    }

    unsigned short* buf  = isv ? vc : kc;
    unsigned short* bufc = isv ? vcls : kcls;
    #pragma unroll
    for (int ct = 0; ct < 12; ++ct){
      const int col = 192 + (isv*12 + ct)*16 + col_l;
      short8 b0 = load_frag8(w, flag, (size_t)col*96 + kq);
      short8 b1 = load_frag8(w, flag, (size_t)col*96 + kq + 32);
      short8 b2 = load_frag8(w, flag, (size_t)col*96 + kq + 64);
      float bv = ldf(bias, flag, col);
      floatx4 acc = {0.f,0.f,0.f,0.f};
      acc = __builtin_amdgcn_mfma_f32_16x16x32_bf16(a0, b0, acc, 0,0,0);
      acc = __builtin_amdgcn_mfma_f32_16x16x32_bf16(a1, b1, acc, 0,0,0);
      acc = __builtin_amdgcn_mfma_f32_16x16x32_bf16(a2, b2, acc, 0,0,0);
      const int head = ct / 6;
      const int dstat = (ct % 6) * 16;
      #pragma unroll
      for (int r = 0; r < 4; ++r){
        if (valid[r]){
          float o = acc[r] + bv;
          if (isCls[r]) bufc[(bI[r]*2 + head)*96 + dstat + col_l] = f2b(o);
          else          buf[baseI[r] + head*96 + dstat + col_l]   = f2b(o);
        }
      }
    }
  }
}

// ---------------- K2: merged pooling (q-pool blocks, then kv-pool x3 blocks) --------
__global__ __launch_bounds__(384) void k_pool(
    const void* __restrict__ x,
    const unsigned short* __restrict__ qr, const void* __restrict__ cwq,
    const void* __restrict__ gq, const void* __restrict__ btaq,
    unsigned short* __restrict__ qp,
    const unsigned short* __restrict__ kc, const unsigned short* __restrict__ vc,
    const unsigned short* __restrict__ kcls, const unsigned short* __restrict__ vcls,
    const void* __restrict__ cwk, const void* __restrict__ gk, const void* __restrict__ bk,
    const void* __restrict__ cwv, const void* __restrict__ gv, const void* __restrict__ bv,
    unsigned short* __restrict__ kp, unsigned short* __restrict__ vt)
{
  const int flag = detect_f32(x);
  const int tid = threadIdx.x;
  if (blockIdx.x < 1792){
    // ================= Q-pool path =================
    __shared__ float wlds[27*96];
    __shared__ float gls[96], bls[96];
    __shared__ float ls1[29*12], ls2[29*12];
    __shared__ float lmean[29], linvs[29];

    const int bid = blockIdx.x;
    const int y  = bid % 28;
    const int t  = (bid / 28) % 8;
    const int bh = bid / 224;
    const bool has_cls = (y == 0 && t == 0);

    for (int idx = tid; idx < 27*96; idx += 384){
      int tap = idx / 96, d = idx - tap*96;
      wlds[idx] = ldf(cwq, flag, d*27 + tap);
    }
    for (int idx = tid; idx < 96; idx += 384){
      gls[idx] = ldf(gq, flag, idx); bls[idx] = ldf(btaq, flag, idx);
    }
    __syncthreads();

    const int xx0 = tid / 12, dg = tid - xx0*12;
    const unsigned short* rowb = qr + (size_t)(bh*6 + (dg >> 1))*TOKSTRIDE + (dg & 1)*8;
    float val[8] = {0,0,0,0,0,0,0,0};

    if (xx0 < 28){
      #pragma unroll
      for (int dt = 0; dt < 3; ++dt){
        int tt = t + dt - 1; if (tt < 0 || tt >= 8) continue;
        #pragma unroll
        for (int dy = 0; dy < 3; ++dy){
          int yy = 2*y + dy - 1; if (yy < 0 || yy >= 56) continue;
          #pragma unroll
          for (int dx = 0; dx < 3; ++dx){
            int xv = 2*xx0 + dx - 1; if (xv < 0 || xv >= 56) continue;
            const int tap = (dt*3+dy)*3+dx;
            short8 v = *(const short8*)(rowb + (size_t)(1 + (tt*56 + yy)*56 + xv)*16);
            const float* wr = wlds + tap*96 + dg*8;
            #pragma unroll
            for (int j = 0; j < 8; ++j) val[j] += b2f((unsigned short)v[j]) * wr[j];
          }
        }
      }
      float s1 = 0.f, s2 = 0.f;
      #pragma unroll
      for (int j = 0; j < 8; ++j){ s1 += val[j]; s2 += val[j]*val[j]; }
      ls1[xx0*12+dg] = s1; ls2[xx0*12+dg] = s2;
    } else if (has_cls && tid >= 348 && tid < 360){
      int cdg = tid - 348;
      const unsigned short* rowc = qr + (size_t)(bh*6 + (cdg >> 1))*TOKSTRIDE + (cdg & 1)*8;
      short8 v = *(const short8*)(rowc);
      float s1 = 0.f, s2 = 0.f;
      #pragma unroll
      for (int j = 0; j < 8; ++j){ val[j] = b2f((unsigned short)v[j]); s1 += val[j]; s2 += val[j]*val[j]; }
      ls1[28*12+cdg] = s1; ls2[28*12+cdg] = s2;
    }
    __syncthreads();

    if (tid < 28 || (tid == 28 && has_cls)){
      float s1 = 0.f, s2 = 0.f;
      #pragma unroll
      for (int k = 0; k < 12; ++k){ s1 += ls1[tid*12+k]; s2 += ls2[tid*12+k]; }
      float mean = s1 * (1.f/96.f);
      float var  = s2 * (1.f/96.f) - mean*mean;
      lmean[tid] = mean; linvs[tid] = rsqrtf(var + 1e-5f);
    }
    __syncthreads();

    if (xx0 < 28){
      float mean = lmean[xx0], inv = linvs[xx0];
      int tok = 1 + (t*28 + y)*28 + xx0;
      short8 o;
      #pragma unroll
      for (int j = 0; j < 8; ++j)
        o[j] = (short)f2b((val[j] - mean)*inv*gls[dg*8+j] + bls[dg*8+j]);
      *(short8*)(qp + ((size_t)bh*6273 + tok)*96 + dg*8) = o;
    } else if (has_cls && tid >= 348 && tid < 360){
      int cdg = tid - 348;
      float mean = lmean[28], inv = linvs[28];
      short8 o;
      #pragma unroll
      for (int j = 0; j < 8; ++j)
        o[j] = (short)f2b((val[j] - mean)*inv*gls[cdg*8+j] + bls[cdg*8+j]);
      *(short8*)(qp + (size_t)bh*6273*96 + cdg*8) = o;
    }
  } else {
    // ================= KV-pool path: 3 units of 128 threads =================
    __shared__ float r1[3][128], r2s[3][128];
    const int unit = tid >> 7;              // 0..2
    const int d = tid & 127;
    const int u = (blockIdx.x - 1792)*3 + unit;
    const bool live = (u < 6656);
    int isv = 0, bh = 0, key = 0;
    if (live){
      isv = u / 3328; int rem = u - isv*3328;
      bh = rem / 416; key = rem - bh*416;
    }
    const bool pad = (key >= 393);
    const int b = bh >> 1, head = bh & 1;
    const unsigned short* buf  = isv ? vc : kc;
    const unsigned short* bufc = isv ? vcls : kcls;
    const void* cw = (isv == 0) ? cwk : cwv;
    const void* g  = (isv == 0) ? gk : gv;
    const void* bt = (isv == 0) ? bk : bv;

    float val = 0.f;
    if (live && !pad && d < 96){
      if (key == 0) val = b2f(bufc[bh*96 + d]);
      else {
        int s = key - 1; int t = s / 49; int r2 = s - t*49; int y = r2 / 7; int xx = r2 - y*7;
        float sum = 0.f;
        #pragma unroll
        for (int dt = 0; dt < 3; ++dt){
          int tt = t + dt - 1; if (tt < 0 || tt >= 8) continue;
          #pragma unroll
          for (int dy = 0; dy < 3; ++dy){
            if (y == 0 && dy == 0) continue;
            int ry = (y == 0) ? (dy - 1) : 2 + 3*(y-1) + dy;
            #pragma unroll
            for (int dx = 0; dx < 3; ++dx){
              if (xx == 0 && dx == 0) continue;
              int rx = (xx == 0) ? (dx - 1) : 2 + 3*(xx-1) + dx;
              sum += b2f(buf[(((b*8 + tt)*20 + ry)*20 + rx)*192 + head*96 + d])
                   * ldf(cw, flag, d*27 + (dt*3+dy)*3+dx);
            }
          }
        }
        val = sum;
      }
    }
    r1[unit][d]  = (d < 96) ? val : 0.f;
    r2s[unit][d] = (d < 96) ? val*val : 0.f;
    __syncthreads();
    for (int off = 64; off > 0; off >>= 1){
      if (d < off){ r1[unit][d] += r1[unit][d+off]; r2s[unit][d] += r2s[unit][d+off]; }
      __syncthreads();
    }
    if (live && d < 96){
      float mean = r1[unit][0] * (1.f/96.f);
      float var  = r2s[unit][0] * (1.f/96.f) - mean*mean;
      float inv = rsqrtf(var + 1e-5f);
      float o = pad ? 0.f : (val - mean)*inv*ldf(g, flag, d) + ldf(bt, flag, d);
      if (isv == 0) kp[((size_t)bh*416 + key)*96 + d] = f2b(o);
      else          vt[((size_t)bh*96 + d)*416 + key] = f2b(o);
    }
  }
}

// ---------------- K4: fused attention — 4 waves split the KEYS of one 16-q tile ------
// rel table TRANSPOSED [slot][16]: per key-tile the 4-row gather is one ds_read_b128.
#define PSTR 424
__global__ __launch_bounds__(256) void k_attn(
    const void* __restrict__ x,
    const unsigned short* __restrict__ qp, const unsigned short* __restrict__ kp,
    const unsigned short* __restrict__ vt,
    const void* __restrict__ rph, const void* __restrict__ rpw,
    const void* __restrict__ rpt,
    unsigned short* __restrict__ ao)
{
  __shared__ unsigned short P[16*PSTR];              // 13.6 KB
  __shared__ __align__(16) float rel[24*16];         // 1.5 KB, [slot][m]
  __shared__ float mx_sh[4][16], sum_sh[4][16];

  const int flag = detect_f32(x);
  const int bh = blockIdx.y;
  const int bb = bh >> 1, head = bh & 1;
  const int tid = threadIdx.x;
  const int lane = tid & 63;
  const int wv = tid >> 6;                   // 0..3
  const int q0 = blockIdx.x * 16;

  const unsigned short* qbase = qp + (size_t)bh*6273*96;
  const unsigned short* kbase = kp + (size_t)bh*416*96;
  const unsigned short* vbase = vt + (size_t)bh*96*416;

  const int col = lane & 15;
  const int quad = lane >> 4;
  const int kq = quad * 8;

  // Q A-fragments (rows = col)
  short8 a0, a1, a2;
  {
    int qa = q0 + col; if (qa > 6272) qa = 6272;
    const unsigned short* qrow = qbase + (size_t)qa*96 + kq;
    a0 = *(const short8*)(qrow);
    a1 = *(const short8*)(qrow + 32);
    a2 = *(const short8*)(qrow + 64);
  }

  // per-row coords (C-layout rows m = quad*4+r)
  int yq4[4], xq4[4], tq4[4], livx[4], liv[4];
  #pragma unroll
  for (int r = 0; r < 4; ++r){
    int gq = q0 + quad*4 + r;
    liv[r]  = (gq >= 1);
    livx[r] = (gq >= 1 && gq <= 6272);
    int s = (gq >= 1) ? gq - 1 : 0;
    tq4[r] = s / 784; int r2 = s - tq4[r]*784; yq4[r] = r2 / 28; xq4[r] = r2 - yq4[r]*28;
  }

  // ---- shared rel GEMM: wave wv computes column tiles wv*2, wv*2+1 ----
  #pragma unroll
  for (int j = 0; j < 2; ++j){
    const int c = (wv*2 + j)*16 + col;
    const void* rsrc; int rrow;
    if (c < 55){ rsrc = rph; rrow = c; }
    else if (c < 110){ rsrc = rpw; rrow = c - 55; }
    else { int ci = c - 110; if (ci > 14) ci = 14; rsrc = rpt; rrow = ci; }
    short8 b0 = load_frag8(rsrc, flag, (size_t)rrow*96 + kq);
    short8 b1 = load_frag8(rsrc, flag, (size_t)rrow*96 + kq + 32);
    short8 b2 = load_frag8(rsrc, flag, (size_t)rrow*96 + kq + 64);
    floatx4 rc = {0.f,0.f,0.f,0.f};
    rc = __builtin_amdgcn_mfma_f32_16x16x32_bf16(a0, b0, rc, 0,0,0);
    rc = __builtin_amdgcn_mfma_f32_16x16x32_bf16(a1, b1, rc, 0,0,0);
    rc = __builtin_amdgcn_mfma_f32_16x16x32_bf16(a2, b2, rc, 0,0,0);
    #pragma unroll
    for (int r = 0; r < 4; ++r){
      if (!livx[r]) continue;
      const int m = quad*4 + r;
      if (c < 55){
        int u = yq4[r] + 24 - c;
        if (u >= 0 && u <= 24 && (u & 3) == 0) rel[(u >> 2)*16 + m] = rc[r];
      } else if (c < 110){
        int u = xq4[r] + 24 - (c - 55);
        if (u >= 0 && u <= 24 && (u & 3) == 0) rel[(8 + (u >> 2))*16 + m] = rc[r];
      } else if (c < 125){
        int u = tq4[r] + 7 - (c - 110);
        if (u >= 0 && u <= 7) rel[(16 + u)*16 + m] = rc[r];
      }
    }
  }
  __syncthreads();

  // QK^T over 7 literal tiles (t clamped to 25; clamp dups are all-pad)
  floatx4 acc[7];
  float mx[4] = {-1e30f,-1e30f,-1e30f,-1e30f};
  #pragma unroll
  for (int i = 0; i < 7; ++i){
    int t = wv*7 + i; if (t > 25) t = 25;
    const unsigned short* krow = kbase + (size_t)(t*16 + col)*96 + kq;
    short8 b0 = *(const short8*)(krow);
    short8 b1 = *(const short8*)(krow + 32);
    short8 b2 = *(const short8*)(krow + 64);
    floatx4 a = {0.f,0.f,0.f,0.f};
    a = __builtin_amdgcn_mfma_f32_16x16x32_bf16(a0, b0, a, 0,0,0);
    a = __builtin_amdgcn_mfma_f32_16x16x32_bf16(a1, b1, a, 0,0,0);
    a = __builtin_amdgcn_mfma_f32_16x16x32_bf16(a2, b2, a, 0,0,0);
    const int key = t*16 + col;
    const bool validk = (key < 393);
    int kt = 0, ky = 0, kx = 0;
    if (key >= 1 && validk){
      int ks = key - 1; kt = ks / 49; int krm = ks - kt*49; ky = krm / 7; kx = krm - ky*7;
    }
    // one b128 per table: 4 rows at once
    floatx4v rh = *(const floatx4v*)(rel + ky*16 + quad*4);
    floatx4v rw = *(const floatx4v*)(rel + (8 + kx)*16 + quad*4);
    floatx4v rt = *(const floatx4v*)(rel + (16 + kt)*16 + quad*4);
    #pragma unroll
    for (int r = 0; r < 4; ++r){
      float s;
      if (!validk) s = -1e30f;
      else {
        s = a[r] * SCALE_F;
        if (key >= 1 && liv[r]) s += rh[r] + rw[r] + rt[r];
      }
      a[r] = s;
      mx[r] = fmaxf(mx[r], s);
    }
    acc[i] = a;
  }
  #pragma unroll
  for (int r = 0; r < 4; ++r){
    #pragma unroll
    for (int o = 1; o < 16; o <<= 1) mx[r] = fmaxf(mx[r], __shfl_xor(mx[r], o, 64));
  }
  if (col == 0){
    #pragma unroll
    for (int r = 0; r < 4; ++r) mx_sh[wv][quad*4 + r] = mx[r];
  }
  __syncthreads();

  // combined max, exp, partial sums, write P quarter
  float M[4];
  #pragma unroll
  for (int r = 0; r < 4; ++r){
    float m01 = fmaxf(mx_sh[0][quad*4 + r], mx_sh[1][quad*4 + r]);
    float m23 = fmaxf(mx_sh[2][quad*4 + r], mx_sh[3][quad*4 + r]);
    M[r] = fmaxf(m01, m23);
  }
  float sum[4] = {0.f,0.f,0.f,0.f};
  #pragma unroll
  for (int i = 0; i < 7; ++i){
    #pragma unroll
    for (int r = 0; r < 4; ++r){
      float e = __expf(acc[i][r] - M[r]);
      acc[i][r] = e; sum[r] += e;
    }
  }
  #pragma unroll
  for (int r = 0; r < 4; ++r){
    #pragma unroll
    for (int o = 1; o < 16; o <<= 1) sum[r] += __shfl_xor(sum[r], o, 64);
  }
  if (col == 0){
    #pragma unroll
    for (int r = 0; r < 4; ++r) sum_sh[wv][quad*4 + r] = sum[r];
  }
  #pragma unroll
  for (int i = 0; i < 7; ++i){
    int t = wv*7 + i; if (t > 25) t = 25;
    #pragma unroll
    for (int r = 0; r < 4; ++r)
      P[(quad*4 + r)*PSTR + t*16 + col] = f2b(acc[i][r]);
  }
  __syncthreads();

  // total sums; PV: 2 slots per wave (mod 6 — wave 3 dups tiles 0,1 identically)
  float linv4[4];
  #pragma unroll
  for (int r = 0; r < 4; ++r)
    linv4[r] = 1.f / (sum_sh[0][quad*4 + r] + sum_sh[1][quad*4 + r]
                    + sum_sh[2][quad*4 + r] + sum_sh[3][quad*4 + r]);

  short8 pf[13];
  #pragma unroll
  for (int s = 0; s < 13; ++s)
    pf[s] = *(const short8*)(P + col*PSTR + s*32 + kq);

  #pragma unroll
  for (int dti = 0; dti < 2; ++dti){
    int slot = wv*2 + dti; if (slot >= 6) slot -= 6;
    const int dd = slot*16 + col;
    const unsigned short* vrow = vbase + (size_t)dd*416 + kq;
    floatx4 o = {0.f,0.f,0.f,0.f};
    #pragma unroll
    for (int s = 0; s < 13; ++s){
      short8 vf = *(const short8*)(vrow + s*32);
      o = __builtin_amdgcn_mfma_f32_16x16x32_bf16(pf[s], vf, o, 0,0,0);
    }
    #pragma unroll
    for (int r = 0; r < 4; ++r){
      int gq = q0 + quad*4 + r;
      if (gq <= 6272){
        float val = o[r] * linv4[r] + b2f(qbase[(size_t)gq*96 + dd]);
        ao[((size_t)bb*6273 + gq)*192 + head*96 + dd] = f2b(val);
      }
    }
  }
}

// ---------------- K5: proj GEMM (self-converting; flag-aware output dtype) ----------
__global__ __launch_bounds__(256) void k_proj(
    const void* __restrict__ x,
    const unsigned short* __restrict__ ao, const void* __restrict__ w,
    const void* __restrict__ bias, void* __restrict__ out)
{
  const int flag = detect_f32(x);
  const int lane = threadIdx.x & 63;
  const int wv = threadIdx.x >> 6;
  const int c = blockIdx.y*64 + wv*16 + (lane & 15);
  const int kq = (lane >> 4) * 8;
  short8 bfr[6];
  #pragma unroll
  for (int s = 0; s < 6; ++s) bfr[s] = load_frag8(w, flag, (size_t)c*192 + kq + 32*s);
  float bv = ldf(bias, flag, c);
  const int m_base = blockIdx.x * 64;
  for (int i = 0; i < 4; ++i){
    int mt = m_base + i*16;
    int ma = mt + (lane & 15); if (ma > 25091) ma = 25091;
    const unsigned short* arow = ao + (size_t)ma*192 + kq;
    floatx4 acc = {0.f,0.f,0.f,0.f};
    #pragma unroll
    for (int s = 0; s < 6; ++s){
      short8 a = *(const short8*)(arow + 32*s);
      acc = __builtin_amdgcn_mfma_f32_16x16x32_bf16(a, bfr[s], acc, 0,0,0);
    }
    #pragma unroll
    for (int r = 0; r < 4; ++r){
      int m = mt + (lane >> 4)*4 + r;
      if (m < 25092){
        float o = acc[r] + bv;
        if (flag) ((float*)out)[(size_t)m*192 + c] = o;
        else      ((unsigned short*)out)[(size_t)m*192 + c] = f2b(o);
      }
    }
  }
}

extern "C" void kernel_launch(void* const* d_in, const int* in_sizes, int n_in,
                              void* d_out, int out_size, void* d_ws, size_t ws_size,
                              hipStream_t stream)
{
  char* p = (char*)d_ws;
  unsigned short* q_raw  = (unsigned short*)p; p += (size_t)19268352*2;
  unsigned short* kc     = (unsigned short*)p; p += (size_t)2457600*2;
  unsigned short* vc     = (unsigned short*)p; p += (size_t)2457600*2;
  unsigned short* kcls   = (unsigned short*)p; p += (size_t)768*2;
  unsigned short* vcls   = (unsigned short*)p; p += (size_t)768*2;
  unsigned short* q_pool = (unsigned short*)p; p += (size_t)4817664*2;
  unsigned short* kp_buf = (unsigned short*)p; p += (size_t)319488*2;
  unsigned short* v_t    = (unsigned short*)p; p += (size_t)319488*2;
  unsigned short* a_out  = q_raw;   // q_raw dead after k_pool

  const void* x      = d_in[0];
  const void* qkv_w  = d_in[1];
  const void* qkv_b  = d_in[2];
  const void* proj_w = d_in[3];
  const void* proj_b = d_in[4];
  const void* pq_w   = d_in[5];
  const void* nq_g   = d_in[6];
  const void* nq_b   = d_in[7];
  const void* pk_w   = d_in[8];
  const void* nk_g   = d_in[9];
  const void* nk_b   = d_in[10];
  const void* pv_w   = d_in[11];
  const void* nv_g   = d_in[12];
  const void* nv_b   = d_in[13];
  const void* rph    = d_in[14];
  const void* rpw    = d_in[15];
  const void* rpt    = d_in[16];

  k_qkv  <<<dim3(1971), 256, 0, stream>>>(x, qkv_w, qkv_b, q_raw, kc, vc, kcls, vcls);
  k_pool <<<dim3(4011), 384, 0, stream>>>(x, q_raw, pq_w, nq_g, nq_b, q_pool,
                                          kc, vc, kcls, vcls,
                                          pk_w, nk_g, nk_b, pv_w, nv_g, nv_b, kp_buf, v_t);
  k_attn <<<dim3(393, 8), 256, 0, stream>>>(x, q_pool, kp_buf, v_t, rph, rpw, rpt, a_out);
  k_proj <<<dim3(393, 3), 256, 0, stream>>>(x, a_out, proj_w, proj_b, d_out);
}

// Round 17
// 267.804 us; speedup vs baseline: 1.2161x; 1.2161x over previous
//
#include <hip/hip_runtime.h>
#include <hip/hip_bf16.h>

typedef short short8 __attribute__((ext_vector_type(8)));
typedef float floatx4 __attribute__((ext_vector_type(4)));
typedef float floatx4v __attribute__((ext_vector_type(4)));

#define SCALE_F 0.10206207261596575f
#define TOKSTRIDE 401424   // 25089 * 16

static __device__ __forceinline__ float b2f(unsigned short u){
  unsigned int v = ((unsigned int)u) << 16; float f;
  __builtin_memcpy(&f, &v, 4); return f;
}
static __device__ __forceinline__ unsigned short f2b(float f){
  __hip_bfloat16 h = __float2bfloat16(f);
  unsigned short u; __builtin_memcpy(&u, &h, 2); return u;
}
static __device__ __forceinline__ int map20(int i){
  return (i < 2) ? i : 7 + ((i-2)/3)*8 + ((i-2)%3);
}

struct ConvDesc {
  const void* src[17];
  long long off[17];
  int count[17];
};

// ---------------- K0: dtype detect + convert SMALL tensors (1..16) to bf16 ------------
__global__ __launch_bounds__(256) void k_convert(ConvDesc d, unsigned short* dst_base,
                                                 int* flagp, const unsigned int* xprobe)
{
  __shared__ int sflag;
  if (threadIdx.x < 64){
    unsigned int w = xprobe[1024 + threadIdx.x];
    int e = (w >> 7) & 0xFF;
    int pl = (e >= 90 && e <= 140) ? 1 : 0;
    unsigned long long m = __ballot(pl);
    if (threadIdx.x == 0){
      sflag = (__popcll(m) < 40) ? 1 : 0;   // 1 = inputs are fp32
      if (blockIdx.x == 0 && blockIdx.y == 0) *flagp = sflag;
    }
  }
  __syncthreads();
  const int flag = sflag;
  const int t = blockIdx.y + 1;             // skip x (tensor 0)
  const int cnt = d.count[t];
  unsigned short* dst = dst_base + d.off[t];
  const float* sf = (const float*)d.src[t];
  const unsigned short* su = (const unsigned short*)d.src[t];
  for (int i = blockIdx.x*blockDim.x + threadIdx.x; i < cnt; i += gridDim.x*blockDim.x){
    dst[i] = flag ? f2b(sf[i]) : su[i];
  }
}

// load one 16-row A-fragment triple from x (flag-dependent dtype)
static __device__ __forceinline__ void load_x_frag(
    const void* xr_, int flag, size_t elem_off, short8& a0, short8& a1, short8& a2)
{
  if (flag){
    const float* xr = (const float*)xr_ + elem_off;
    floatx4v f0 = *(const floatx4v*)(xr),      f1 = *(const floatx4v*)(xr+4);
    floatx4v f2 = *(const floatx4v*)(xr+32),   f3 = *(const floatx4v*)(xr+36);
    floatx4v f4 = *(const floatx4v*)(xr+64),   f5 = *(const floatx4v*)(xr+68);
    #pragma unroll
    for (int j = 0; j < 4; ++j){
      a0[j] = (short)f2b(f0[j]); a0[j+4] = (short)f2b(f1[j]);
      a1[j] = (short)f2b(f2[j]); a1[j+4] = (short)f2b(f3[j]);
      a2[j] = (short)f2b(f4[j]); a2[j+4] = (short)f2b(f5[j]);
    }
  } else {
    const unsigned short* xr = (const unsigned short*)xr_ + elem_off;
    a0 = *(const short8*)(xr);
    a1 = *(const short8*)(xr + 32);
    a2 = *(const short8*)(xr + 64);
  }
}

// ---------------- K1: merged QKV GEMM ----------------
__global__ __launch_bounds__(256) void k_qkv(
    const void* __restrict__ x, const unsigned short* __restrict__ w,
    const unsigned short* __restrict__ bias, unsigned short* __restrict__ qr,
    unsigned short* __restrict__ kc, unsigned short* __restrict__ vc,
    unsigned short* __restrict__ kcls, unsigned short* __restrict__ vcls,
    const int* __restrict__ flagp)
{
  const int flag = *flagp;
  const int lane = threadIdx.x & 63;
  const int wv = threadIdx.x >> 6;
  const int kq = (lane >> 4) * 8;
  const int quad = lane >> 4;
  const int col_l = lane & 15;

  if (blockIdx.x < 1569){
    // ---- Q path ----
    const int m_base = blockIdx.x * 64 + wv * 16;
    int ma = m_base + col_l; if (ma > 100355) ma = 100355;
    short8 a0, a1, a2;
    load_x_frag(x, flag, (size_t)ma*96 + kq, a0, a1, a2);

    int bbase[4], ntok[4], mrow[4];
    #pragma unroll
    for (int r = 0; r < 4; ++r){
      int m = m_base + quad*4 + r;
      mrow[r] = m;
      int bb = m / 25089;
      ntok[r] = m - bb*25089;
      bbase[r] = bb*2;
    }

    #pragma unroll
    for (int ct = 0; ct < 12; ++ct){
      int col = ct*16 + col_l;
      const unsigned short* wrow = w + col*96 + kq;
      short8 b0 = *(const short8*)(wrow);
      short8 b1 = *(const short8*)(wrow + 32);
      short8 b2 = *(const short8*)(wrow + 64);
      float bv = b2f(bias[col]);
      floatx4 acc = {0.f,0.f,0.f,0.f};
      acc = __builtin_amdgcn_mfma_f32_16x16x32_bf16(a0, b0, acc, 0,0,0);
      acc = __builtin_amdgcn_mfma_f32_16x16x32_bf16(a1, b1, acc, 0,0,0);
      acc = __builtin_amdgcn_mfma_f32_16x16x32_bf16(a2, b2, acc, 0,0,0);
      const int head = ct / 6;
      const int dt6  = ct % 6;
      #pragma unroll
      for (int r = 0; r < 4; ++r){
        if (mrow[r] < 100356)
          qr[(size_t)((bbase[r]+head)*6 + dt6)*TOKSTRIDE + (size_t)ntok[r]*16 + col_l]
            = f2b(acc[r] + bv);
      }
    }
  } else {
    // ---- KV path ----
    const int id = blockIdx.x - 1569;
    const int isv = id / 201;
    const int bx = id - isv*201;
    const int rbase = bx * 64 + wv * 16;

    int rhoA = rbase + col_l; if (rhoA > 12803) rhoA = 12803;
    int bA, nA;
    if (rhoA < 4){ bA = rhoA; nA = 0; }
    else {
      int rp = rhoA - 4;
      bA = rp / 3200; int rem = rp - bA*3200;
      int t = rem / 400; int s = rem - t*400;
      int ry = s / 20, rx = s - ry*20;
      nA = 1 + (t*56 + map20(ry))*56 + map20(rx);
    }
    short8 a0, a1, a2;
    load_x_frag(x, flag, ((size_t)bA*25089 + nA)*96 + kq, a0, a1, a2);

    int isCls[4], bI[4], baseI[4], valid[4];
    #pragma unroll
    for (int r = 0; r < 4; ++r){
      int rho = rbase + quad*4 + r;
      valid[r] = (rho < 12804);
      if (rho > 12803) rho = 12803;
      if (rho < 4){ isCls[r] = 1; bI[r] = rho; baseI[r] = 0; }
      else {
        int rp = rho - 4;
        int b = rp / 3200; int rem = rp - b*3200;
        int t = rem / 400; int s = rem - t*400;
        int ry = s / 20, rx = s - ry*20;
        isCls[r] = 0; bI[r] = b;
        baseI[r] = (((b*8 + t)*20 + ry)*20 + rx)*192;
      }
    }

    unsigned short* buf  = isv ? vc : kc;
    unsigned short* bufc = isv ? vcls : kcls;
    #pragma unroll
    for (int ct = 0; ct < 12; ++ct){
      const int col = 192 + (isv*12 + ct)*16 + col_l;
      const unsigned short* wrow = w + col*96 + kq;
      short8 b0 = *(const short8*)(wrow);
      short8 b1 = *(const short8*)(wrow + 32);
      short8 b2 = *(const short8*)(wrow + 64);
      float bv = b2f(bias[col]);
      floatx4 acc = {0.f,0.f,0.f,0.f};
      acc = __builtin_amdgcn_mfma_f32_16x16x32_bf16(a0, b0, acc, 0,0,0);
      acc = __builtin_amdgcn_mfma_f32_16x16x32_bf16(a1, b1, acc, 0,0,0);
      acc = __builtin_amdgcn_mfma_f32_16x16x32_bf16(a2, b2, acc, 0,0,0);
      const int head = ct / 6;
      const int dstat = (ct % 6) * 16;
      #pragma unroll
      for (int r = 0; r < 4; ++r){
        if (valid[r]){
          float o = acc[r] + bv;
          if (isCls[r]) bufc[(bI[r]*2 + head)*96 + dstat + col_l] = f2b(o);
          else          buf[baseI[r] + head*96 + dstat + col_l]   = f2b(o);
        }
      }
    }
  }
}

// ---------------- K2: merged pooling (q-pool blocks, then kv-pool x3 blocks) --------
__global__ __launch_bounds__(384) void k_pool(
    const unsigned short* __restrict__ qr, const unsigned short* __restrict__ cwq,
    const unsigned short* __restrict__ gq, const unsigned short* __restrict__ btaq,
    unsigned short* __restrict__ qp,
    const unsigned short* __restrict__ kc, const unsigned short* __restrict__ vc,
    const unsigned short* __restrict__ kcls, const unsigned short* __restrict__ vcls,
    const unsigned short* __restrict__ cwk, const unsigned short* __restrict__ gk, const unsigned short* __restrict__ bk,
    const unsigned short* __restrict__ cwv, const unsigned short* __restrict__ gv, const unsigned short* __restrict__ bv,
    unsigned short* __restrict__ kp, unsigned short* __restrict__ vt)
{
  const int tid = threadIdx.x;
  if (blockIdx.x < 1792){
    // ================= Q-pool path =================
    __shared__ float wlds[27*96];
    __shared__ float gls[96], bls[96];
    __shared__ float ls1[29*12], ls2[29*12];
    __shared__ float lmean[29], linvs[29];

    const int bid = blockIdx.x;
    const int y  = bid % 28;
    const int t  = (bid / 28) % 8;
    const int bh = bid / 224;
    const bool has_cls = (y == 0 && t == 0);

    for (int idx = tid; idx < 27*96; idx += 384){
      int tap = idx / 96, d = idx - tap*96;
      wlds[idx] = b2f(cwq[d*27 + tap]);
    }
    for (int idx = tid; idx < 96; idx += 384){
      gls[idx] = b2f(gq[idx]); bls[idx] = b2f(btaq[idx]);
    }
    __syncthreads();

    const int x = tid / 12, dg = tid - x*12;
    const unsigned short* rowb = qr + (size_t)(bh*6 + (dg >> 1))*TOKSTRIDE + (dg & 1)*8;
    float val[8] = {0,0,0,0,0,0,0,0};

    if (x < 28){
      #pragma unroll
      for (int dt = 0; dt < 3; ++dt){
        int tt = t + dt - 1; if (tt < 0 || tt >= 8) continue;
        #pragma unroll
        for (int dy = 0; dy < 3; ++dy){
          int yy = 2*y + dy - 1; if (yy < 0 || yy >= 56) continue;
          #pragma unroll
          for (int dx = 0; dx < 3; ++dx){
            int xv = 2*x + dx - 1; if (xv < 0 || xv >= 56) continue;
            const int tap = (dt*3+dy)*3+dx;
            short8 v = *(const short8*)(rowb + (size_t)(1 + (tt*56 + yy)*56 + xv)*16);
            const float* wr = wlds + tap*96 + dg*8;
            #pragma unroll
            for (int j = 0; j < 8; ++j) val[j] += b2f((unsigned short)v[j]) * wr[j];
          }
        }
      }
      float s1 = 0.f, s2 = 0.f;
      #pragma unroll
      for (int j = 0; j < 8; ++j){ s1 += val[j]; s2 += val[j]*val[j]; }
      ls1[x*12+dg] = s1; ls2[x*12+dg] = s2;
    } else if (has_cls && tid >= 348 && tid < 360){
      int cdg = tid - 348;
      const unsigned short* rowc = qr + (size_t)(bh*6 + (cdg >> 1))*TOKSTRIDE + (cdg & 1)*8;
      short8 v = *(const short8*)(rowc);
      float s1 = 0.f, s2 = 0.f;
      #pragma unroll
      for (int j = 0; j < 8; ++j){ val[j] = b2f((unsigned short)v[j]); s1 += val[j]; s2 += val[j]*val[j]; }
      ls1[28*12+cdg] = s1; ls2[28*12+cdg] = s2;
    }
    __syncthreads();

    if (tid < 28 || (tid == 28 && has_cls)){
      float s1 = 0.f, s2 = 0.f;
      #pragma unroll
      for (int k = 0; k < 12; ++k){ s1 += ls1[tid*12+k]; s2 += ls2[tid*12+k]; }
      float mean = s1 * (1.f/96.f);
      float var  = s2 * (1.f/96.f) - mean*mean;
      lmean[tid] = mean; linvs[tid] = rsqrtf(var + 1e-5f);
    }
    __syncthreads();

    if (x < 28){
      float mean = lmean[x], inv = linvs[x];
      int tok = 1 + (t*28 + y)*28 + x;
      short8 o;
      #pragma unroll
      for (int j = 0; j < 8; ++j)
        o[j] = (short)f2b((val[j] - mean)*inv*gls[dg*8+j] + bls[dg*8+j]);
      *(short8*)(qp + ((size_t)bh*6273 + tok)*96 + dg*8) = o;
    } else if (has_cls && tid >= 348 && tid < 360){
      int cdg = tid - 348;
      float mean = lmean[28], inv = linvs[28];
      short8 o;
      #pragma unroll
      for (int j = 0; j < 8; ++j)
        o[j] = (short)f2b((val[j] - mean)*inv*gls[cdg*8+j] + bls[cdg*8+j]);
      *(short8*)(qp + (size_t)bh*6273*96 + cdg*8) = o;
    }
  } else {
    // ================= KV-pool path: 3 units of 128 threads =================
    __shared__ float r1[3][128], r2s[3][128];
    const int unit = tid >> 7;              // 0..2
    const int d = tid & 127;
    const int u = (blockIdx.x - 1792)*3 + unit;
    const bool live = (u < 6656);
    int isv = 0, bh = 0, key = 0;
    if (live){
      isv = u / 3328; int rem = u - isv*3328;
      bh = rem / 416; key = rem - bh*416;
    }
    const bool pad = (key >= 393);
    const int b = bh >> 1, head = bh & 1;
    const unsigned short* buf  = isv ? vc : kc;
    const unsigned short* bufc = isv ? vcls : kcls;
    const unsigned short* cw = (isv == 0) ? cwk : cwv;
    const unsigned short* g  = (isv == 0) ? gk : gv;
    const unsigned short* bt = (isv == 0) ? bk : bv;

    float val = 0.f;
    if (live && !pad && d < 96){
      if (key == 0) val = b2f(bufc[bh*96 + d]);
      else {
        int s = key - 1; int t = s / 49; int r2 = s - t*49; int y = r2 / 7; int xx = r2 - y*7;
        const unsigned short* wr = cw + d*27;
        float sum = 0.f;
        #pragma unroll
        for (int dt = 0; dt < 3; ++dt){
          int tt = t + dt - 1; if (tt < 0 || tt >= 8) continue;
          #pragma unroll
          for (int dy = 0; dy < 3; ++dy){
            if (y == 0 && dy == 0) continue;
            int ry = (y == 0) ? (dy - 1) : 2 + 3*(y-1) + dy;
            #pragma unroll
            for (int dx = 0; dx < 3; ++dx){
              if (xx == 0 && dx == 0) continue;
              int rx = (xx == 0) ? (dx - 1) : 2 + 3*(xx-1) + dx;
              sum += b2f(buf[(((b*8 + tt)*20 + ry)*20 + rx)*192 + head*96 + d]) * b2f(wr[(dt*3+dy)*3+dx]);
            }
          }
        }
        val = sum;
      }
    }
    r1[unit][d]  = (d < 96) ? val : 0.f;
    r2s[unit][d] = (d < 96) ? val*val : 0.f;
    __syncthreads();
    for (int off = 64; off > 0; off >>= 1){
      if (d < off){ r1[unit][d] += r1[unit][d+off]; r2s[unit][d] += r2s[unit][d+off]; }
      __syncthreads();
    }
    if (live && d < 96){
      float mean = r1[unit][0] * (1.f/96.f);
      float var  = r2s[unit][0] * (1.f/96.f) - mean*mean;
      float inv = rsqrtf(var + 1e-5f);
      float o = pad ? 0.f : (val - mean)*inv*b2f(g[d]) + b2f(bt[d]);
      if (isv == 0) kp[((size_t)bh*416 + key)*96 + d] = f2b(o);
      else          vt[((size_t)bh*96 + d)*416 + key] = f2b(o);
    }
  }
}

// ---------------- K4: fused attention — 4 waves split the KEYS of one 16-q tile ------
// rel table TRANSPOSED [slot][16]: per key-tile the 4-row gather is one ds_read_b128
// per table (3 total) instead of 12 scalar b32 reads.
#define PSTR 424
__global__ __launch_bounds__(256) void k_attn(
    const unsigned short* __restrict__ qp, const unsigned short* __restrict__ kp,
    const unsigned short* __restrict__ vt,
    const unsigned short* __restrict__ rph, const unsigned short* __restrict__ rpw,
    const unsigned short* __restrict__ rpt,
    unsigned short* __restrict__ ao)
{
  __shared__ unsigned short P[16*PSTR];              // 13.6 KB
  __shared__ __align__(16) float rel[24*16];         // 1.5 KB, [slot][m]
  __shared__ float mx_sh[4][16], sum_sh[4][16];

  const int bh = blockIdx.y;
  const int bb = bh >> 1, head = bh & 1;
  const int tid = threadIdx.x;
  const int lane = tid & 63;
  const int wv = tid >> 6;                   // 0..3
  const int q0 = blockIdx.x * 16;

  const unsigned short* qbase = qp + (size_t)bh*6273*96;
  const unsigned short* kbase = kp + (size_t)bh*416*96;
  const unsigned short* vbase = vt + (size_t)bh*96*416;

  const int col = lane & 15;
  const int quad = lane >> 4;
  const int kq = quad * 8;

  // Q A-fragments (rows = col)
  short8 a0, a1, a2;
  {
    int qa = q0 + col; if (qa > 6272) qa = 6272;
    const unsigned short* qrow = qbase + (size_t)qa*96 + kq;
    a0 = *(const short8*)(qrow);
    a1 = *(const short8*)(qrow + 32);
    a2 = *(const short8*)(qrow + 64);
  }

  // per-row coords (C-layout rows m = quad*4+r)
  int yq4[4], xq4[4], tq4[4], livx[4], liv[4];
  #pragma unroll
  for (int r = 0; r < 4; ++r){
    int gq = q0 + quad*4 + r;
    liv[r]  = (gq >= 1);
    livx[r] = (gq >= 1 && gq <= 6272);
    int s = (gq >= 1) ? gq - 1 : 0;
    tq4[r] = s / 784; int r2 = s - tq4[r]*784; yq4[r] = r2 / 28; xq4[r] = r2 - yq4[r]*28;
  }

  // ---- shared rel GEMM: wave wv computes column tiles wv*2, wv*2+1 ----
  #pragma unroll
  for (int j = 0; j < 2; ++j){
    const int c = (wv*2 + j)*16 + col;
    const unsigned short* rrow;
    if (c < 55)       rrow = rph + (size_t)c*96;
    else if (c < 110) rrow = rpw + (size_t)(c-55)*96;
    else { int ci = c-110; if (ci > 14) ci = 14; rrow = rpt + (size_t)ci*96; }
    rrow += kq;
    short8 b0 = *(const short8*)(rrow);
    short8 b1 = *(const short8*)(rrow + 32);
    short8 b2 = *(const short8*)(rrow + 64);
    floatx4 rc = {0.f,0.f,0.f,0.f};
    rc = __builtin_amdgcn_mfma_f32_16x16x32_bf16(a0, b0, rc, 0,0,0);
    rc = __builtin_amdgcn_mfma_f32_16x16x32_bf16(a1, b1, rc, 0,0,0);
    rc = __builtin_amdgcn_mfma_f32_16x16x32_bf16(a2, b2, rc, 0,0,0);
    #pragma unroll
    for (int r = 0; r < 4; ++r){
      if (!livx[r]) continue;
      const int m = quad*4 + r;
      if (c < 55){
        int u = yq4[r] + 24 - c;
        if (u >= 0 && u <= 24 && (u & 3) == 0) rel[(u >> 2)*16 + m] = rc[r];
      } else if (c < 110){
        int u = xq4[r] + 24 - (c - 55);
        if (u >= 0 && u <= 24 && (u & 3) == 0) rel[(8 + (u >> 2))*16 + m] = rc[r];
      } else if (c < 125){
        int u = tq4[r] + 7 - (c - 110);
        if (u >= 0 && u <= 7) rel[(16 + u)*16 + m] = rc[r];
      }
    }
  }
  __syncthreads();

  // QK^T over 7 literal tiles (t clamped to 25; clamp dups are all-pad)
  floatx4 acc[7];
  float mx[4] = {-1e30f,-1e30f,-1e30f,-1e30f};
  #pragma unroll
  for (int i = 0; i < 7; ++i){
    int t = wv*7 + i; if (t > 25) t = 25;
    const unsigned short* krow = kbase + (size_t)(t*16 + col)*96 + kq;
    short8 b0 = *(const short8*)(krow);
    short8 b1 = *(const short8*)(krow + 32);
    short8 b2 = *(const short8*)(krow + 64);
    floatx4 a = {0.f,0.f,0.f,0.f};
    a = __builtin_amdgcn_mfma_f32_16x16x32_bf16(a0, b0, a, 0,0,0);
    a = __builtin_amdgcn_mfma_f32_16x16x32_bf16(a1, b1, a, 0,0,0);
    a = __builtin_amdgcn_mfma_f32_16x16x32_bf16(a2, b2, a, 0,0,0);
    const int key = t*16 + col;
    const bool validk = (key < 393);
    int kt = 0, ky = 0, kx = 0;
    if (key >= 1 && validk){
      int ks = key - 1; kt = ks / 49; int krm = ks - kt*49; ky = krm / 7; kx = krm - ky*7;
    }
    // one b128 per table: 4 rows at once
    floatx4v rh = *(const floatx4v*)(rel + ky*16 + quad*4);
    floatx4v rw = *(const floatx4v*)(rel + (8 + kx)*16 + quad*4);
    floatx4v rt = *(const floatx4v*)(rel + (16 + kt)*16 + quad*4);
    #pragma unroll
    for (int r = 0; r < 4; ++r){
      float s;
      if (!validk) s = -1e30f;
      else {
        s = a[r] * SCALE_F;
        if (key >= 1 && liv[r]) s += rh[r] + rw[r] + rt[r];
      }
      a[r] = s;
      mx[r] = fmaxf(mx[r], s);
    }
    acc[i] = a;
  }
  #pragma unroll
  for (int r = 0; r < 4; ++r){
    #pragma unroll
    for (int o = 1; o < 16; o <<= 1) mx[r] = fmaxf(mx[r], __shfl_xor(mx[r], o, 64));
  }
  if (col == 0){
    #pragma unroll
    for (int r = 0; r < 4; ++r) mx_sh[wv][quad*4 + r] = mx[r];
  }
  __syncthreads();

  // combined max, exp, partial sums, write P quarter
  float M[4];
  #pragma unroll
  for (int r = 0; r < 4; ++r){
    float m01 = fmaxf(mx_sh[0][quad*4 + r], mx_sh[1][quad*4 + r]);
    float m23 = fmaxf(mx_sh[2][quad*4 + r], mx_sh[3][quad*4 + r]);
    M[r] = fmaxf(m01, m23);
  }
  float sum[4] = {0.f,0.f,0.f,0.f};
  #pragma unroll
  for (int i = 0; i < 7; ++i){
    #pragma unroll
    for (int r = 0; r < 4; ++r){
      float e = __expf(acc[i][r] - M[r]);
      acc[i][r] = e; sum[r] += e;
    }
  }
  #pragma unroll
  for (int r = 0; r < 4; ++r){
    #pragma unroll
    for (int o = 1; o < 16; o <<= 1) sum[r] += __shfl_xor(sum[r], o, 64);
  }
  if (col == 0){
    #pragma unroll
    for (int r = 0; r < 4; ++r) sum_sh[wv][quad*4 + r] = sum[r];
  }
  #pragma unroll
  for (int i = 0; i < 7; ++i){
    int t = wv*7 + i; if (t > 25) t = 25;
    #pragma unroll
    for (int r = 0; r < 4; ++r)
      P[(quad*4 + r)*PSTR + t*16 + col] = f2b(acc[i][r]);
  }
  __syncthreads();

  // total sums; PV: 2 slots per wave (mod 6 — wave 3 dups tiles 0,1 identically)
  float linv4[4];
  #pragma unroll
  for (int r = 0; r < 4; ++r)
    linv4[r] = 1.f / (sum_sh[0][quad*4 + r] + sum_sh[1][quad*4 + r]
                    + sum_sh[2][quad*4 + r] + sum_sh[3][quad*4 + r]);

  short8 pf[13];
  #pragma unroll
  for (int s = 0; s < 13; ++s)
    pf[s] = *(const short8*)(P + col*PSTR + s*32 + kq);

  #pragma unroll
  for (int dti = 0; dti < 2; ++dti){
    int slot = wv*2 + dti; if (slot >= 6) slot -= 6;
    const int dd = slot*16 + col;
    const unsigned short* vrow = vbase + (size_t)dd*416 + kq;
    floatx4 o = {0.f,0.f,0.f,0.f};
    #pragma unroll
    for (int s = 0; s < 13; ++s){
      short8 vf = *(const short8*)(vrow + s*32);
      o = __builtin_amdgcn_mfma_f32_16x16x32_bf16(pf[s], vf, o, 0,0,0);
    }
    #pragma unroll
    for (int r = 0; r < 4; ++r){
      int gq = q0 + quad*4 + r;
      if (gq <= 6272){
        float val = o[r] * linv4[r] + b2f(qbase[(size_t)gq*96 + dd]);
        ao[((size_t)bb*6273 + gq)*192 + head*96 + dd] = f2b(val);
      }
    }
  }
}

// ---------------- K5: proj GEMM (flag-aware output dtype) ----------------
__global__ __launch_bounds__(256) void k_proj(
    const unsigned short* __restrict__ ao, const unsigned short* __restrict__ w,
    const unsigned short* __restrict__ bias, void* __restrict__ out, const int* __restrict__ flagp)
{
  const int flag = *flagp;
  const int lane = threadIdx.x & 63;
  const int wv = threadIdx.x >> 6;
  const int c = blockIdx.y*64 + wv*16 + (lane & 15);
  const int kq = (lane >> 4) * 8;
  short8 bfr[6];
  const unsigned short* wrow = w + c*192 + kq;
  #pragma unroll
  for (int s = 0; s < 6; ++s) bfr[s] = *(const short8*)(wrow + 32*s);
  float bv = b2f(bias[c]);
  const int m_base = blockIdx.x * 64;
  for (int i = 0; i < 4; ++i){
    int mt = m_base + i*16;
    int ma = mt + (lane & 15); if (ma > 25091) ma = 25091;
    const unsigned short* arow = ao + (size_t)ma*192 + kq;
    floatx4 acc = {0.f,0.f,0.f,0.f};
    #pragma unroll
    for (int s = 0; s < 6; ++s){
      short8 a = *(const short8*)(arow + 32*s);
      acc = __builtin_amdgcn_mfma_f32_16x16x32_bf16(a, bfr[s], acc, 0,0,0);
    }
    #pragma unroll
    for (int r = 0; r < 4; ++r){
      int m = mt + (lane >> 4)*4 + r;
      if (m < 25092){
        float o = acc[r] + bv;
        if (flag) ((float*)out)[(size_t)m*192 + c] = o;
        else      ((unsigned short*)out)[(size_t)m*192 + c] = f2b(o);
      }
    }
  }
}

extern "C" void kernel_launch(void* const* d_in, const int* in_sizes, int n_in,
                              void* d_out, int out_size, void* d_ws, size_t ws_size,
                              hipStream_t stream)
{
  char* p = (char*)d_ws;
  int* flagp = (int*)p; p += 16;
  unsigned short* conv = (unsigned short*)p;

  ConvDesc desc;
  long long cum = 0;
  for (int i = 0; i < 17; ++i){
    desc.src[i] = d_in[i];
    desc.off[i] = cum;
    desc.count[i] = in_sizes[i];
    cum += in_sizes[i];
  }
  p += (size_t)cum * 2;

  unsigned short* q_raw  = (unsigned short*)p; p += (size_t)19268352*2;
  unsigned short* kc     = (unsigned short*)p; p += (size_t)2457600*2;
  unsigned short* vc     = (unsigned short*)p; p += (size_t)2457600*2;
  unsigned short* kcls   = (unsigned short*)p; p += (size_t)768*2;
  unsigned short* vcls   = (unsigned short*)p; p += (size_t)768*2;
  unsigned short* q_pool = (unsigned short*)p; p += (size_t)4817664*2;
  unsigned short* kp_buf = (unsigned short*)p; p += (size_t)319488*2;
  unsigned short* v_t    = (unsigned short*)p; p += (size_t)319488*2;
  unsigned short* a_out  = q_raw;   // q_raw dead after k_pool

  const unsigned short* cqkv_w = conv + desc.off[1];
  const unsigned short* cqkv_b = conv + desc.off[2];
  const unsigned short* cproj_w= conv + desc.off[3];
  const unsigned short* cproj_b= conv + desc.off[4];
  const unsigned short* cpq_w  = conv + desc.off[5];
  const unsigned short* cnq_g  = conv + desc.off[6];
  const unsigned short* cnq_b  = conv + desc.off[7];
  const unsigned short* cpk_w  = conv + desc.off[8];
  const unsigned short* cnk_g  = conv + desc.off[9];
  const unsigned short* cnk_b  = conv + desc.off[10];
  const unsigned short* cpv_w  = conv + desc.off[11];
  const unsigned short* cnv_g  = conv + desc.off[12];
  const unsigned short* cnv_b  = conv + desc.off[13];
  const unsigned short* crph   = conv + desc.off[14];
  const unsigned short* crpw   = conv + desc.off[15];
  const unsigned short* crpt   = conv + desc.off[16];

  k_convert<<<dim3(16, 16), 256, 0, stream>>>(desc, conv, flagp, (const unsigned int*)d_in[0]);
  k_qkv  <<<dim3(1971), 256, 0, stream>>>(d_in[0], cqkv_w, cqkv_b, q_raw, kc, vc, kcls, vcls, flagp);
  k_pool <<<dim3(4011), 384, 0, stream>>>(q_raw, cpq_w, cnq_g, cnq_b, q_pool,
                                          kc, vc, kcls, vcls,
                                          cpk_w, cnk_g, cnk_b, cpv_w, cnv_g, cnv_b, kp_buf, v_t);
  k_attn <<<dim3(393, 8), 256, 0, stream>>>(q_pool, kp_buf, v_t, crph, crpw, crpt, a_out);
  k_proj <<<dim3(393, 3), 256, 0, stream>>>(a_out, cproj_w, cproj_b, d_out, flagp);
}